// Round 6
// baseline (66.714 us; speedup 1.0000x reference)
//
#include <hip/hip_runtime.h>

// FractalEmbedding: tokens -> Julia features (16 fp32) -> 16x2048 projection.
// Output 268 MB fp32 => store-bandwidth-bound (~38 us at the 7 TB/s the
// harness's own fillBuffer sustains).
//
// R6 = R5 (best: 58.6 us) + two isolated changes:
//  (1) nontemporal float2 stores in proj (L2 no-allocate for the 268 MB
//      write-once stream),
//  (2) feats kernel re-gridded 128x256 -> 512x64 (all 256 CUs, latency-bound).

constexpr int TOKENS = 4 * 8192;   // 32768
constexpr int EMBED  = 2048;
constexpr int NF     = 16;         // 2 * STEPS
constexpr int STEPS  = 8;
constexpr int TB     = 64;         // tokens per block

typedef float f32x2 __attribute__((ext_vector_type(2)));
typedef float f32x4 __attribute__((ext_vector_type(4)));

// ---------------- kernel 1: Julia features ----------------
__global__ __launch_bounds__(64)
void feats_kernel(const int* __restrict__ tok,
                  const float* __restrict__ crt,
                  const float* __restrict__ cit,
                  float* __restrict__ feats)   // [TOKENS][NF]
{
    const int t = blockIdx.x * 64 + threadIdx.x;
    const int id = tok[t];
    const float cr = crt[id];
    const float ci = cit[id];
    float f[NF];
    float zr = 0.0f, zi = 0.0f;
    #pragma unroll
    for (int st = 0; st < STEPS; ++st) {
        const float nzr = zr * zr - zi * zi + cr;
        const float nzi = 2.0f * zr * zi + ci;
        zr = nzr; zi = nzi;
        f[2 * st]     = zr;
        f[2 * st + 1] = zi;
    }
    f32x4* fo = reinterpret_cast<f32x4*>(feats + (size_t)t * NF);
    #pragma unroll
    for (int j = 0; j < 4; ++j) {
        f32x4 v = { f[4 * j], f[4 * j + 1], f[4 * j + 2], f[4 * j + 3] };
        fo[j] = v;
    }
}

// ---------------- kernel 2: projection ----------------
// grid: 4 d-chunks (512 dims) minor x 512 token-groups (64 tokens) major.
__global__ __launch_bounds__(256, 5)
void proj_kernel(const float* __restrict__ feats,  // [TOKENS][NF]
                 const float* __restrict__ W,      // [EMBED][NF]
                 const float* __restrict__ scale_p,
                 float* __restrict__ out)          // [TOKENS][EMBED]
{
    const int tid  = threadIdx.x;
    const int dblk = blockIdx.x & 3;
    const int tblk = blockIdx.x >> 2;
    const int d0   = dblk * 512 + tid * 2;   // this thread's dim pair
    const float s  = scale_p[0];

    // w2[k] = { W[d0][k], W[d0+1][k] } * s  -> 16 packed pairs (32 VGPR).
    f32x2 w2[NF];
    {
        const f32x4* W4 = reinterpret_cast<const f32x4*>(W + (size_t)d0 * NF);
        #pragma unroll
        for (int k = 0; k < 4; ++k) {
            f32x4 a = W4[k];       // row d0, feats 4k..4k+3
            f32x4 b = W4[4 + k];   // row d0+1
            w2[4 * k + 0] = (f32x2){ a.x * s, b.x * s };
            w2[4 * k + 1] = (f32x2){ a.y * s, b.y * s };
            w2[4 * k + 2] = (f32x2){ a.z * s, b.z * s };
            w2[4 * k + 3] = (f32x2){ a.w * s, b.w * s };
        }
    }

    const float* fbase = feats + (size_t)tblk * TB * NF;
    f32x2* __restrict__ out2 = reinterpret_cast<f32x2*>(out);
    const int obase = dblk * 256 + tid;      // float2 units within a row
    const size_t orow0 = (size_t)tblk * TB * (EMBED / 2) + obase;

    for (int i = 0; i < TB; i += 2) {
        // Two independent token chains in flight (wave-uniform addresses).
        float fa[NF], fb[NF];
        {
            const f32x4* fpa = reinterpret_cast<const f32x4*>(fbase + i * NF);
            const f32x4* fpb = reinterpret_cast<const f32x4*>(fbase + (i + 1) * NF);
            #pragma unroll
            for (int k = 0; k < 4; ++k) {
                f32x4 va = fpa[k], vb = fpb[k];
                fa[4 * k + 0] = va.x; fa[4 * k + 1] = va.y;
                fa[4 * k + 2] = va.z; fa[4 * k + 3] = va.w;
                fb[4 * k + 0] = vb.x; fb[4 * k + 1] = vb.y;
                fb[4 * k + 2] = vb.z; fb[4 * k + 3] = vb.w;
            }
        }
        f32x2 accA = (f32x2){0.0f, 0.0f};
        f32x2 accB = (f32x2){0.0f, 0.0f};
        #pragma unroll
        for (int k = 0; k < NF; ++k) {
            accA += (f32x2){ fa[k], fa[k] } * w2[k];   // v_pk_fma_f32
            accB += (f32x2){ fb[k], fb[k] } * w2[k];
        }
        __builtin_nontemporal_store(accA, &out2[orow0 + (size_t)i       * (EMBED / 2)]);
        __builtin_nontemporal_store(accB, &out2[orow0 + (size_t)(i + 1) * (EMBED / 2)]);
    }
}

// ---------------- fallback (fused) if ws too small ----------------
__global__ __launch_bounds__(512)
void fused_kernel(const int* __restrict__ tok,
                  const float* __restrict__ crt,
                  const float* __restrict__ cit,
                  const float* __restrict__ W,
                  const float* __restrict__ scale_p,
                  float* __restrict__ out)
{
    const int tid = threadIdx.x;
    const float s = scale_p[0];
    float w[4][NF];
    {
        const float4* W4 = reinterpret_cast<const float4*>(W + (size_t)tid * 4 * NF);
        #pragma unroll
        for (int r = 0; r < 4; ++r)
            #pragma unroll
            for (int k = 0; k < 4; ++k) {
                float4 v = W4[r * 4 + k];
                w[r][k * 4 + 0] = v.x; w[r][k * 4 + 1] = v.y;
                w[r][k * 4 + 2] = v.z; w[r][k * 4 + 3] = v.w;
            }
    }
    __shared__ float feats[64][NF];
    const int tok0 = blockIdx.x * 64;
    if (tid < 64) {
        const int t = tok[tok0 + tid];
        const float cr = crt[t], ci = cit[t];
        float zr = 0.0f, zi = 0.0f;
        #pragma unroll
        for (int st = 0; st < STEPS; ++st) {
            const float nzr = zr * zr - zi * zi + cr;
            const float nzi = 2.0f * zr * zi + ci;
            zr = nzr; zi = nzi;
            feats[tid][2 * st] = zr; feats[tid][2 * st + 1] = zi;
        }
    }
    __syncthreads();
    float4* out4 = reinterpret_cast<float4*>(out);
    for (int i = 0; i < 64; ++i) {
        float f[NF];
        const float4* fp = reinterpret_cast<const float4*>(feats[i]);
        #pragma unroll
        for (int k = 0; k < 4; ++k) {
            float4 v = fp[k];
            f[k * 4 + 0] = v.x; f[k * 4 + 1] = v.y;
            f[k * 4 + 2] = v.z; f[k * 4 + 3] = v.w;
        }
        float acc[4];
        #pragma unroll
        for (int r = 0; r < 4; ++r) {
            float a = 0.0f;
            #pragma unroll
            for (int k = 0; k < NF; ++k) a = fmaf(f[k], w[r][k], a);
            acc[r] = a * s;
        }
        out4[(size_t)(tok0 + i) * (EMBED / 4) + tid] =
            make_float4(acc[0], acc[1], acc[2], acc[3]);
    }
}

extern "C" void kernel_launch(void* const* d_in, const int* in_sizes, int n_in,
                              void* d_out, int out_size, void* d_ws, size_t ws_size,
                              hipStream_t stream) {
    const int*   tok   = (const int*)d_in[0];
    const float* crt   = (const float*)d_in[1];
    const float* cit   = (const float*)d_in[2];
    const float* W     = (const float*)d_in[3];
    const float* scale = (const float*)d_in[4];
    float*       out   = (float*)d_out;

    const size_t feats_bytes = (size_t)TOKENS * NF * sizeof(float);
    if (ws_size >= feats_bytes) {
        float* feats = (float*)d_ws;
        feats_kernel<<<TOKENS / 64, 64, 0, stream>>>(tok, crt, cit, feats);
        proj_kernel<<<4 * (TOKENS / TB), 256, 0, stream>>>(feats, W, scale, out);
    } else {
        fused_kernel<<<TOKENS / 64, 512, 0, stream>>>(tok, crt, cit, W, scale, out);
    }
}

// Round 7
// 54.297 us; speedup vs baseline: 1.2287x; 1.2287x over previous
//
#include <hip/hip_runtime.h>

// FractalEmbedding: tokens -> Julia features (16 fp32) -> 16x2048 projection.
// Output 268 MB fp32 => store-bandwidth-bound (~38 us at the 7 TB/s the
// harness's own fillBuffer sustains at 10% occupancy / 8 VGPR).
//
// R7: single fused kernel. Each block owns a CONTIGUOUS 512 KB output region
// (64 tokens x full 2048-dim row, written row-sequentially). 512 thr x 4
// dims/thread; W in regs (scale folded, pk_fma pairs); feats computed once
// per block into 4 KB LDS (one barrier), read via broadcast ds_read_b128.
// NO nontemporal stores (R6 proved them -8 us). 2-token ILP unroll from R5.

constexpr int TOKENS = 4 * 8192;   // 32768
constexpr int EMBED  = 2048;
constexpr int NF     = 16;         // 2 * STEPS
constexpr int STEPS  = 8;
constexpr int TB     = 64;         // tokens per block

typedef float f32x2 __attribute__((ext_vector_type(2)));
typedef float f32x4 __attribute__((ext_vector_type(4)));

__global__ __launch_bounds__(512, 4)   // 4 waves/SIMD = 2 blocks/CU, caps VGPR<=128
void fused_kernel(const int* __restrict__ tok,
                  const float* __restrict__ crt,
                  const float* __restrict__ cit,
                  const float* __restrict__ W,      // [EMBED][NF]
                  const float* __restrict__ scale_p,
                  float* __restrict__ out)          // [TOKENS][EMBED]
{
    const int tid = threadIdx.x;
    const int d0  = tid * 4;                 // 4 consecutive dims per thread
    const float s = scale_p[0];

    // Weights for dims d0..d0+3, scale folded, packed for v_pk_fma_f32:
    // wp[p][k] = { W[d0+2p][k], W[d0+2p+1][k] } * s
    f32x2 wp[2][NF];
    {
        const f32x4* W4 = reinterpret_cast<const f32x4*>(W + (size_t)d0 * NF);
        #pragma unroll
        for (int p = 0; p < 2; ++p) {
            #pragma unroll
            for (int k = 0; k < 4; ++k) {
                f32x4 a = W4[p * 8 + k];       // row d0+2p
                f32x4 b = W4[p * 8 + 4 + k];   // row d0+2p+1
                wp[p][4 * k + 0] = (f32x2){ a.x * s, b.x * s };
                wp[p][4 * k + 1] = (f32x2){ a.y * s, b.y * s };
                wp[p][4 * k + 2] = (f32x2){ a.z * s, b.z * s };
                wp[p][4 * k + 3] = (f32x2){ a.w * s, b.w * s };
            }
        }
    }

    // Julia features for this block's 64 tokens -> LDS (4 KB).
    __shared__ float feats[TB][NF];
    const int tok0 = blockIdx.x * TB;
    if (tid < TB) {
        const int t = tok[tok0 + tid];
        const float cr = crt[t];
        const float ci = cit[t];
        float zr = 0.0f, zi = 0.0f;
        #pragma unroll
        for (int st = 0; st < STEPS; ++st) {
            const float nzr = zr * zr - zi * zi + cr;
            const float nzi = 2.0f * zr * zi + ci;
            zr = nzr; zi = nzi;
            feats[tid][2 * st]     = zr;
            feats[tid][2 * st + 1] = zi;
        }
    }
    __syncthreads();

    // Row-sequential contiguous writes: token i occupies an 8 KB row; this
    // block's 64 rows form one contiguous 512 KB region.
    float* __restrict__ obase = out + (size_t)tok0 * EMBED + d0;

    for (int i = 0; i < TB; i += 2) {
        float fa[NF], fb[NF];
        {
            const f32x4* fpa = reinterpret_cast<const f32x4*>(feats[i]);
            const f32x4* fpb = reinterpret_cast<const f32x4*>(feats[i + 1]);
            #pragma unroll
            for (int k = 0; k < 4; ++k) {
                f32x4 va = fpa[k], vb = fpb[k];
                fa[4 * k + 0] = va.x; fa[4 * k + 1] = va.y;
                fa[4 * k + 2] = va.z; fa[4 * k + 3] = va.w;
                fb[4 * k + 0] = vb.x; fb[4 * k + 1] = vb.y;
                fb[4 * k + 2] = vb.z; fb[4 * k + 3] = vb.w;
            }
        }
        f32x2 aA0 = {0.f, 0.f}, aA1 = {0.f, 0.f};
        f32x2 aB0 = {0.f, 0.f}, aB1 = {0.f, 0.f};
        #pragma unroll
        for (int k = 0; k < NF; ++k) {
            const f32x2 fA = { fa[k], fa[k] };
            const f32x2 fB = { fb[k], fb[k] };
            aA0 += fA * wp[0][k];   // v_pk_fma_f32
            aA1 += fA * wp[1][k];
            aB0 += fB * wp[0][k];
            aB1 += fB * wp[1][k];
        }
        f32x4 oA = { aA0.x, aA0.y, aA1.x, aA1.y };
        f32x4 oB = { aB0.x, aB0.y, aB1.x, aB1.y };
        *reinterpret_cast<f32x4*>(obase + (size_t)i       * EMBED) = oA;
        *reinterpret_cast<f32x4*>(obase + (size_t)(i + 1) * EMBED) = oB;
    }
}

extern "C" void kernel_launch(void* const* d_in, const int* in_sizes, int n_in,
                              void* d_out, int out_size, void* d_ws, size_t ws_size,
                              hipStream_t stream) {
    const int*   tok   = (const int*)d_in[0];
    const float* crt   = (const float*)d_in[1];
    const float* cit   = (const float*)d_in[2];
    const float* W     = (const float*)d_in[3];
    const float* scale = (const float*)d_in[4];
    float*       out   = (float*)d_out;

    fused_kernel<<<TOKENS / TB, 512, 0, stream>>>(tok, crt, cit, W, scale, out);
}

// Round 8
// 53.008 us; speedup vs baseline: 1.2586x; 1.0243x over previous
//
#include <hip/hip_runtime.h>

// FractalEmbedding: tokens -> Julia features (16 fp32) -> 16x2048 projection.
// Output 268 MB fp32 => store-bound (~38-43 us floor at fill's 7 TB/s).
//
// R8 theory: R7's LDS broadcast was SATURATED (84 B/cy/CU = ds_read_b128
// ceiling): every thread read 64 B feats per 16 B output. Fix: 8 dims/thread
// (256 thr), so LDS bytes per output byte drop 4:1 -> 2:1 (~42 B/cy/CU).
// Dims split as two chunks (tid*4 and 1024+tid*4) so each of the 4 stores
// per 2-token iter is a fully contiguous 1 KB wave burst. Keeps R7 wins:
// fused feats in LDS, contiguous 512 KB/block, pk_fma, 2-token unroll,
// plain (non-nt) stores.

constexpr int TOKENS = 4 * 8192;   // 32768
constexpr int EMBED  = 2048;
constexpr int NF     = 16;         // 2 * STEPS
constexpr int STEPS  = 8;
constexpr int TB     = 64;         // tokens per block

typedef float f32x2 __attribute__((ext_vector_type(2)));
typedef float f32x4 __attribute__((ext_vector_type(4)));

__global__ __launch_bounds__(256, 2)
void fused_kernel(const int* __restrict__ tok,
                  const float* __restrict__ crt,
                  const float* __restrict__ cit,
                  const float* __restrict__ W,      // [EMBED][NF]
                  const float* __restrict__ scale_p,
                  float* __restrict__ out)          // [TOKENS][EMBED]
{
    const int tid  = threadIdx.x;
    const int dlo  = tid * 4;          // chunk 0: dims dlo..dlo+3
    const int dhi  = 1024 + tid * 4;   // chunk 1: dims dhi..dhi+3
    const float s  = scale_p[0];

    // Packed weights, scale folded: wp[c][p][k] = {W[d+2p][k], W[d+2p+1][k]}*s
    // c=0 -> dlo, c=1 -> dhi. 2*2*16 f32x2 = 128 VGPR.
    f32x2 wp[2][2][NF];
    #pragma unroll
    for (int c = 0; c < 2; ++c) {
        const int d = (c == 0) ? dlo : dhi;
        const f32x4* W4 = reinterpret_cast<const f32x4*>(W + (size_t)d * NF);
        #pragma unroll
        for (int p = 0; p < 2; ++p) {
            #pragma unroll
            for (int k = 0; k < 4; ++k) {
                f32x4 a = W4[p * 8 + k];       // row d+2p
                f32x4 b = W4[p * 8 + 4 + k];   // row d+2p+1
                wp[c][p][4 * k + 0] = (f32x2){ a.x * s, b.x * s };
                wp[c][p][4 * k + 1] = (f32x2){ a.y * s, b.y * s };
                wp[c][p][4 * k + 2] = (f32x2){ a.z * s, b.z * s };
                wp[c][p][4 * k + 3] = (f32x2){ a.w * s, b.w * s };
            }
        }
    }

    // Julia features for this block's 64 tokens -> LDS (4 KB).
    __shared__ float feats[TB][NF];
    const int tok0 = blockIdx.x * TB;
    if (tid < TB) {
        const int t = tok[tok0 + tid];
        const float cr = crt[t];
        const float ci = cit[t];
        float zr = 0.0f, zi = 0.0f;
        #pragma unroll
        for (int st = 0; st < STEPS; ++st) {
            const float nzr = zr * zr - zi * zi + cr;
            const float nzi = 2.0f * zr * zi + ci;
            zr = nzr; zi = nzi;
            feats[tid][2 * st]     = zr;
            feats[tid][2 * st + 1] = zi;
        }
    }
    __syncthreads();

    float* __restrict__ olo = out + (size_t)tok0 * EMBED + dlo;
    float* __restrict__ ohi = out + (size_t)tok0 * EMBED + dhi;

    for (int i = 0; i < TB; i += 2) {
        float fa[NF], fb[NF];
        {
            const f32x4* fpa = reinterpret_cast<const f32x4*>(feats[i]);
            const f32x4* fpb = reinterpret_cast<const f32x4*>(feats[i + 1]);
            #pragma unroll
            for (int k = 0; k < 4; ++k) {
                f32x4 va = fpa[k], vb = fpb[k];
                fa[4 * k + 0] = va.x; fa[4 * k + 1] = va.y;
                fa[4 * k + 2] = va.z; fa[4 * k + 3] = va.w;
                fb[4 * k + 0] = vb.x; fb[4 * k + 1] = vb.y;
                fb[4 * k + 2] = vb.z; fb[4 * k + 3] = vb.w;
            }
        }
        f32x2 aL0 = {0.f,0.f}, aL1 = {0.f,0.f}, aH0 = {0.f,0.f}, aH1 = {0.f,0.f};
        f32x2 bL0 = {0.f,0.f}, bL1 = {0.f,0.f}, bH0 = {0.f,0.f}, bH1 = {0.f,0.f};
        #pragma unroll
        for (int k = 0; k < NF; ++k) {
            const f32x2 fA = { fa[k], fa[k] };
            const f32x2 fB = { fb[k], fb[k] };
            aL0 += fA * wp[0][0][k];   // v_pk_fma_f32
            aL1 += fA * wp[0][1][k];
            aH0 += fA * wp[1][0][k];
            aH1 += fA * wp[1][1][k];
            bL0 += fB * wp[0][0][k];
            bL1 += fB * wp[0][1][k];
            bH0 += fB * wp[1][0][k];
            bH1 += fB * wp[1][1][k];
        }
        const size_t r0 = (size_t)i * EMBED;
        const size_t r1 = (size_t)(i + 1) * EMBED;
        *reinterpret_cast<f32x4*>(olo + r0) = (f32x4){ aL0.x, aL0.y, aL1.x, aL1.y };
        *reinterpret_cast<f32x4*>(ohi + r0) = (f32x4){ aH0.x, aH0.y, aH1.x, aH1.y };
        *reinterpret_cast<f32x4*>(olo + r1) = (f32x4){ bL0.x, bL0.y, bL1.x, bL1.y };
        *reinterpret_cast<f32x4*>(ohi + r1) = (f32x4){ bH0.x, bH0.y, bH1.x, bH1.y };
    }
}

extern "C" void kernel_launch(void* const* d_in, const int* in_sizes, int n_in,
                              void* d_out, int out_size, void* d_ws, size_t ws_size,
                              hipStream_t stream) {
    const int*   tok   = (const int*)d_in[0];
    const float* crt   = (const float*)d_in[1];
    const float* cit   = (const float*)d_in[2];
    const float* W     = (const float*)d_in[3];
    const float* scale = (const float*)d_in[4];
    float*       out   = (float*)d_out;

    fused_kernel<<<TOKENS / TB, 256, 0, stream>>>(tok, crt, cit, W, scale, out);
}